// Round 13
// baseline (163.534 us; speedup 1.0000x reference)
//
#include <hip/hip_runtime.h>
#include <hip/hip_bf16.h>
#include <stdint.h>
#include <stddef.h>

// MMD via single signed 2N x 2N RBF gram, lower triangle only.
// Round 13: ONE kernel, no cooperative API (r12's hipLaunchCooperativeKernel
// failed in this harness). Producer-consumer strip flags replace grid.sync():
//  - 512 blocks, launch_bounds(256,2) + 66 KB LDS => statically 2 blocks/CU
//    => all 512 co-resident => spin-waits cannot deadlock.
//  - producer: convert 32 rows -> fp8 + norms; __syncthreads (drains stores
//    to XCD L2); t0 RELEASE/AGENT store flags[bid]=1 (L2 writeback).
//  - consumer: relaxed AGENT spins on needed strip quarters (coherent, no
//    cache-thrash), one __threadfence acquire, then r9's gram phase verbatim.
//  - init-agnostic: absolute flag stores (poison 0xAA != 1); stale 1s benign
//    (Zf8 bytes identical every call). out zeroed via atomicExch + out-flag.
// Phase 1 = r9 structure: MX-fp8 16x16x128 unit scales, 2x2 wave tiling,
// 128x128 tiles, 2x32 KB LDS double buffer, 1 barrier/tile. Strips paired
// (p, 127-p) x 8 column slots -> 16-17 tiles/block, no tail.

#define N_PTS   8192
#define DIM     256
#define TWO_N   16384

#define AS1 __attribute__((address_space(1)))
#define AS3 __attribute__((address_space(3)))

typedef __attribute__((ext_vector_type(4))) float f32x4;
typedef __attribute__((ext_vector_type(4))) int   i32x4;
typedef __attribute__((ext_vector_type(8))) int   i32x8;

__global__ __launch_bounds__(256, 2) void mmd_fused(const float* __restrict__ X,
                                                    const float* __restrict__ Y,
                                                    const int* __restrict__ sigmap,
                                                    unsigned char* __restrict__ Zf8,
                                                    float* __restrict__ n2,
                                                    int* __restrict__ flags,
                                                    float* __restrict__ out) {
    __shared__ char smem_b[65536];   // 2 x 32 KB B-tile buffers, XOR swizzle
    __shared__ float wsum[4];

    const int bid  = (int)blockIdx.x;     // 0..511
    const int t    = threadIdx.x;
    const int wave = t >> 6;
    const int lane = t & 63;

    const float c2 = -1.4426950408889634f / (float)(*sigmap);  // -log2e/sigma
    const float m2 = -2.0f * c2;
    const int   SC = 0x7f7f7f7f;          // unit E8M0 scales (2^0)

    // ================= phase 0: produce own 32 rows =================
    {
        const int row0 = bid * 32 + wave * 8;
#pragma unroll
        for (int i = 0; i < 8; ++i) {
            const int row = row0 + i;
            const float* src = (row < N_PTS) ? (X + (size_t)row * DIM)
                                             : (Y + (size_t)(row - N_PTS) * DIM);
            float4 v = ((const float4*)src)[lane];
            float s = v.x * v.x + v.y * v.y + v.z * v.z + v.w * v.w;
#pragma unroll
            for (int off = 32; off; off >>= 1) s += __shfl_down(s, off, 64);
            if (lane == 0) n2[row] = c2 * s;

            const int p01 = __builtin_amdgcn_cvt_pk_fp8_f32(v.x, v.y, 0, false);
            const int p23 = __builtin_amdgcn_cvt_pk_fp8_f32(v.z, v.w, 0, false);
            const unsigned int pk = ((unsigned)p01 & 0xffffu) | ((unsigned)p23 << 16);
            *(unsigned int*)(Zf8 + (size_t)row * DIM + (size_t)lane * 4) = pk;
        }
    }
    __syncthreads();                      // all waves' stores drained to L2
    if (t == 0) {
        if (bid == 0) {
            atomicExch(out, 0.0f);        // device-coherent zero of the output
            __hip_atomic_store(&flags[512], 1, __ATOMIC_RELEASE, __HIP_MEMORY_SCOPE_AGENT);
        }
        __hip_atomic_store(&flags[bid], 1, __ATOMIC_RELEASE, __HIP_MEMORY_SCOPE_AGENT);
    }

    // ================= wait for every strip this block consumes ==========
    const int p = bid >> 3;               // 0..63 -> strips p and 127-p
    const int c = bid & 7;                // column slot: tiles bc ≡ c (mod 8)
    {
        const int topB = 127 - p;         // widest strip needed (B of phase 1)
        const int nB   = (topB - c) / 8 + 1;
        const int nQ   = nB * 4 + 8;      // B-strip quarters + 2 A-strips x 4
        for (int i = t; i < nQ; i += 256) {
            int strip;
            if (i < nB * 4) strip = c + 8 * (i >> 2);
            else { const int j = i - nB * 4; strip = (j >> 2) ? (127 - p) : p; }
            const int q = i & 3;
            while (__hip_atomic_load(&flags[strip * 4 + q], __ATOMIC_RELAXED,
                                     __HIP_MEMORY_SCOPE_AGENT) != 1)
                __builtin_amdgcn_s_sleep(8);
        }
    }
    __syncthreads();                      // all spins done
    __threadfence();                      // acquire: invalidate stale caches

    // ================= phase 1: signed gram, strips p and 127-p ==========
    const int wm = wave >> 1;
    const int wn = wave & 1;
    const int g  = lane >> 4;
    const int ml = lane & 15;

    float block_acc = 0.0f;

#pragma unroll 1
    for (int ph = 0; ph < 2; ++ph) {
        const int br = ph ? (127 - p) : p;
        const int rowBase = br * 128;
        const int brX = (br < 64);
        if (c > br) continue;             // block-uniform

        // ---- stage first tile (bc = c) into buffer 0 ----
        {
            const int colBase0 = c * 128;
#pragma unroll
            for (int i = 0; i < 8; ++i) {
                const int cidx = i * 256 + t;
                const int col  = cidx >> 4;
                const int s    = cidx & 15;
                const int gc   = s ^ (col & 15);
                const unsigned char* gp = Zf8 + (size_t)(colBase0 + col) * DIM + gc * 16;
                __builtin_amdgcn_global_load_lds((const AS1 void*)gp,
                                                 (AS3 void*)(smem_b + (size_t)cidx * 16), 16, 0, 0);
            }
        }

        // ---- A fragments (full K=256, this wave's 64 rows): 64 VGPRs ----
        i32x8 af[4][2];
#pragma unroll
        for (int mt = 0; mt < 4; ++mt) {
            const unsigned char* rp =
                Zf8 + (size_t)(rowBase + wm * 64 + mt * 16 + ml) * DIM + g * 32;
#pragma unroll
            for (int kc = 0; kc < 2; ++kc) {
                union { i32x4 h[2]; i32x8 v; } u;
                u.h[0] = *(const i32x4*)(rp + kc * 128);
                u.h[1] = *(const i32x4*)(rp + kc * 128 + 16);
                af[mt][kc] = u.v;
            }
        }
        float a_i[4][4];
#pragma unroll
        for (int mt = 0; mt < 4; ++mt)
#pragma unroll
            for (int rr = 0; rr < 4; ++rr)
                a_i[mt][rr] = n2[rowBase + wm * 64 + mt * 16 + g * 4 + rr];

        int cur = 0;
        for (int bc = c; bc <= br; bc += 8) {
            const int colBase = bc * 128;

            float b_j[4];
#pragma unroll
            for (int nt = 0; nt < 4; ++nt)
                b_j[nt] = n2[colBase + wn * 64 + nt * 16 + ml];

            f32x4 acc[4][4] = {};

            __syncthreads();              // current buffer staged; other free

            // stage NEXT tile (overlaps compute)
            if (bc + 8 <= br) {
                const int colBaseN = colBase + 8 * 128;
                char* dst = smem_b + (cur ^ 1) * 32768;
#pragma unroll
                for (int i = 0; i < 8; ++i) {
                    const int cidx = i * 256 + t;
                    const int col  = cidx >> 4;
                    const int s    = cidx & 15;
                    const int gc   = s ^ (col & 15);
                    const unsigned char* gp = Zf8 + (size_t)(colBaseN + col) * DIM + gc * 16;
                    __builtin_amdgcn_global_load_lds((const AS1 void*)gp,
                                                     (AS3 void*)(dst + (size_t)cidx * 16), 16, 0, 0);
                }
            }

            // compute: 2 k-chunks of K=128
            const char* buf = smem_b + cur * 32768;
#pragma unroll
            for (int kc = 0; kc < 2; ++kc) {
                const int j0 = kc * 8 + g * 2;
                i32x8 bf[4];
#pragma unroll
                for (int nt = 0; nt < 4; ++nt) {
                    const char* cb = buf + (size_t)(wn * 64 + nt * 16 + ml) * 256;
                    union { i32x4 h[2]; i32x8 v; } u;
                    u.h[0] = *(const i32x4*)(cb + (size_t)((j0)     ^ ml) * 16);
                    u.h[1] = *(const i32x4*)(cb + (size_t)((j0 + 1) ^ ml) * 16);
                    bf[nt] = u.v;
                }
#pragma unroll
                for (int mt = 0; mt < 4; ++mt)
#pragma unroll
                    for (int nt = 0; nt < 4; ++nt)
                        acc[mt][nt] = __builtin_amdgcn_mfma_scale_f32_16x16x128_f8f6f4(
                            af[mt][kc], bf[nt], acc[mt][nt], 0, 0, 0, SC, 0, SC);
            }

            // epilogue
            float ts0 = 0.f, ts1 = 0.f, ts2 = 0.f, ts3 = 0.f;
#pragma unroll
            for (int mt = 0; mt < 4; ++mt)
#pragma unroll
                for (int nt = 0; nt < 4; ++nt) {
                    const float ab = b_j[nt];
                    ts0 += __builtin_amdgcn_exp2f(fmaf(acc[mt][nt][0], m2, a_i[mt][0] + ab));
                    ts1 += __builtin_amdgcn_exp2f(fmaf(acc[mt][nt][1], m2, a_i[mt][1] + ab));
                    ts2 += __builtin_amdgcn_exp2f(fmaf(acc[mt][nt][2], m2, a_i[mt][2] + ab));
                    ts3 += __builtin_amdgcn_exp2f(fmaf(acc[mt][nt][3], m2, a_i[mt][3] + ab));
                }
            const float tsum = (ts0 + ts1) + (ts2 + ts3);

            const float sgn = ((bc < 64) == brX) ? 1.0f : -1.0f;
            const float w   = (bc == br) ? sgn : 2.0f * sgn;
            block_acc = fmaf(w, tsum, block_acc);
            cur ^= 1;
        }
        __syncthreads();                  // drain before next phase reuses LDS
    }

    // ---- block reduction + single atomic ----
    float s = block_acc;
#pragma unroll
    for (int off = 32; off; off >>= 1) s += __shfl_down(s, off, 64);
    if (lane == 0) wsum[wave] = s;
    __syncthreads();
    if (t == 0) {
        while (__hip_atomic_load(&flags[512], __ATOMIC_ACQUIRE,
                                 __HIP_MEMORY_SCOPE_AGENT) != 1)
            __builtin_amdgcn_s_sleep(8);  // out[0] zeroed (set ~launch+5us)
        atomicAdd(out, (wsum[0] + wsum[1] + wsum[2] + wsum[3]) * (1.0f / 67108864.0f));
    }
}

// ---------------------------------------------------------------------------
extern "C" void kernel_launch(void* const* d_in, const int* in_sizes, int n_in,
                              void* d_out, int out_size, void* d_ws, size_t ws_size,
                              hipStream_t stream) {
    const float* X      = (const float*)d_in[0];
    const float* Y      = (const float*)d_in[1];
    const int*   sigmap = (const int*)d_in[2];
    float*       out    = (float*)d_out;

    unsigned char* Zf8   = (unsigned char*)d_ws;                      // 4 MB
    float*         n2    = (float*)((char*)d_ws + (size_t)TWO_N * DIM);
    int*           flags = (int*)((char*)d_ws + (size_t)TWO_N * DIM + TWO_N * 4);

    mmd_fused<<<512, 256, 0, stream>>>(X, Y, sigmap, Zf8, n2, flags, out);
}

// Round 14
// 121.278 us; speedup vs baseline: 1.3484x; 1.3484x over previous
//
#include <hip/hip_runtime.h>
#include <hip/hip_bf16.h>
#include <stdint.h>
#include <stddef.h>

// MMD via single signed 2N x 2N RBF gram, lower triangle only.
// Round 14: r9 structure + strip-paired work assignment.
// r13 proved the ~50us total-minus-kernel gap is fixed harness overhead
// (single dispatch had the same gap), so back to two kernels; the lever is
// kernel time. r9's heavy-first grid had ~20 tile-times of generation
// imbalance (4 gens of 512: 8+6+4+2). Pairing strips (p, 127-p) makes every
// block ~8 tiles: grid = 64 pairs x 16 column slots = 1024 blocks = 2
// perfectly balanced generations (~16.1 tile-times, -19%).
// Gram body = r9/r13 verbatim: MX-fp8 16x16x128 unit scales, 2x2 wave
// tiling, 128x128 tiles, 2x32 KB LDS double buffer, 1 barrier/tile, (256,2).

#define N_PTS   8192
#define DIM     256
#define TWO_N   16384

#define AS1 __attribute__((address_space(1)))
#define AS3 __attribute__((address_space(3)))

typedef __attribute__((ext_vector_type(4))) float f32x4;
typedef __attribute__((ext_vector_type(4))) int   i32x4;
typedef __attribute__((ext_vector_type(8))) int   i32x8;

// ---------------------------------------------------------------------------
// Prep: fp32 -> fp8 e4m3 (row-major) + c2-scaled fp32 row norms + zero output.
// n2[row] = c2 * |z_row|^2, c2 = -log2e/sigma (epilogue adds directly).
// ---------------------------------------------------------------------------
__global__ __launch_bounds__(256) void mmd_prep(const float* __restrict__ X,
                                                const float* __restrict__ Y,
                                                const int* __restrict__ sigmap,
                                                unsigned char* __restrict__ Zf8,
                                                float* __restrict__ n2,
                                                float* __restrict__ out) {
    if (blockIdx.x == 0 && threadIdx.x == 0) out[0] = 0.0f;

    const int wave = threadIdx.x >> 6;
    const int lane = threadIdx.x & 63;
    const int row  = blockIdx.x * 4 + wave;          // 0 .. TWO_N-1

    const float* src = (row < N_PTS) ? (X + (size_t)row * DIM)
                                     : (Y + (size_t)(row - N_PTS) * DIM);
    float4 v = ((const float4*)src)[lane];           // 64 lanes x 4 = 256

    float s = v.x * v.x + v.y * v.y + v.z * v.z + v.w * v.w;
#pragma unroll
    for (int off = 32; off; off >>= 1) s += __shfl_down(s, off, 64);
    if (lane == 0) {
        const float c2 = -1.4426950408889634f / (float)(*sigmap);
        n2[row] = c2 * s;
    }

    const int p01 = __builtin_amdgcn_cvt_pk_fp8_f32(v.x, v.y, 0, false);
    const int p23 = __builtin_amdgcn_cvt_pk_fp8_f32(v.z, v.w, 0, false);
    const unsigned int pk = ((unsigned)p01 & 0xffffu) | ((unsigned)p23 << 16);
    *(unsigned int*)(Zf8 + (size_t)row * DIM + (size_t)lane * 4) = pk;
}

// ---------------------------------------------------------------------------
// Main. grid = 64*16 = 1024; pair index p = bid>>4 (strips p and 127-p),
// column slot c = bid&15 (tiles bc ≡ c mod 16). Every block ~8 tiles.
// 4 waves in 2x2; wave (wm,wn) owns 64x64 of the 128x128 tile = 4x4 MFMA
// tiles of 16x16x128 MX-fp8 (2 k-chunks of K=128). A frags (full K=256,
// 64 VGPRs) stationary per strip; B tiles (32 KB) double-buffered in LDS.
// ---------------------------------------------------------------------------
__global__ __launch_bounds__(256, 2) void mmd_main(const unsigned char* __restrict__ Zf8,
                                                   const float* __restrict__ n2,
                                                   const int* __restrict__ sigmap,
                                                   float* __restrict__ out) {
    __shared__ char smem_b[65536];   // 2 x 32 KB B-tile buffers, XOR swizzle
    __shared__ float wsum[4];

    const int bid = (int)blockIdx.x;      // 0..1023
    const int p   = bid >> 4;             // 0..63 -> strips p and 127-p
    const int c   = bid & 15;             // column slot

    const int t    = threadIdx.x;
    const int wave = t >> 6;
    const int lane = t & 63;
    const int wm   = wave >> 1;
    const int wn   = wave & 1;
    const int g    = lane >> 4;           // k-quad
    const int ml   = lane & 15;

    const float m2 = 2.8853900817779268f / (float)(*sigmap);   // -2*c2
    const int   SC = 0x7f7f7f7f;          // unit E8M0 scales (2^0)

    float block_acc = 0.0f;

#pragma unroll 1
    for (int ph = 0; ph < 2; ++ph) {
        const int br = ph ? (127 - p) : p;
        const int rowBase = br * 128;
        const int brX = (br < 64);
        if (c > br) continue;             // block-uniform; skip empty strip

        // ---- stage first tile (bc = c) into buffer 0 ----
        {
            const int colBase0 = c * 128;
#pragma unroll
            for (int i = 0; i < 8; ++i) {
                const int cidx = i * 256 + t;          // 0..2047 16B-chunks
                const int col  = cidx >> 4;            // col 0..127
                const int s    = cidx & 15;            // LDS slot
                const int gc   = s ^ (col & 15);       // XOR swizzle on source
                const unsigned char* gp = Zf8 + (size_t)(colBase0 + col) * DIM + gc * 16;
                __builtin_amdgcn_global_load_lds((const AS1 void*)gp,
                                                 (AS3 void*)(smem_b + (size_t)cidx * 16), 16, 0, 0);
            }
        }

        // ---- A fragments (full K=256, this wave's 64 rows): 64 VGPRs ----
        i32x8 af[4][2];
#pragma unroll
        for (int mt = 0; mt < 4; ++mt) {
            const unsigned char* rp =
                Zf8 + (size_t)(rowBase + wm * 64 + mt * 16 + ml) * DIM + g * 32;
#pragma unroll
            for (int kc = 0; kc < 2; ++kc) {
                union { i32x4 h[2]; i32x8 v; } u;
                u.h[0] = *(const i32x4*)(rp + kc * 128);
                u.h[1] = *(const i32x4*)(rp + kc * 128 + 16);
                af[mt][kc] = u.v;
            }
        }
        float a_i[4][4];
#pragma unroll
        for (int mt = 0; mt < 4; ++mt)
#pragma unroll
            for (int rr = 0; rr < 4; ++rr)
                a_i[mt][rr] = n2[rowBase + wm * 64 + mt * 16 + g * 4 + rr];

        int cur = 0;
        for (int bc = c; bc <= br; bc += 16) {
            const int colBase = bc * 128;

            float b_j[4];
#pragma unroll
            for (int nt = 0; nt < 4; ++nt)
                b_j[nt] = n2[colBase + wn * 64 + nt * 16 + ml];

            f32x4 acc[4][4] = {};

            __syncthreads();              // current buffer staged; other free

            // stage NEXT tile (overlaps compute)
            if (bc + 16 <= br) {
                const int colBaseN = colBase + 16 * 128;
                char* dst = smem_b + (cur ^ 1) * 32768;
#pragma unroll
                for (int i = 0; i < 8; ++i) {
                    const int cidx = i * 256 + t;
                    const int col  = cidx >> 4;
                    const int s    = cidx & 15;
                    const int gc   = s ^ (col & 15);
                    const unsigned char* gp = Zf8 + (size_t)(colBaseN + col) * DIM + gc * 16;
                    __builtin_amdgcn_global_load_lds((const AS1 void*)gp,
                                                     (AS3 void*)(dst + (size_t)cidx * 16), 16, 0, 0);
                }
            }

            // compute: 2 k-chunks of K=128
            const char* buf = smem_b + cur * 32768;
#pragma unroll
            for (int kc = 0; kc < 2; ++kc) {
                const int j0 = kc * 8 + g * 2;
                i32x8 bf[4];
#pragma unroll
                for (int nt = 0; nt < 4; ++nt) {
                    const char* cb = buf + (size_t)(wn * 64 + nt * 16 + ml) * 256;
                    union { i32x4 h[2]; i32x8 v; } u;
                    u.h[0] = *(const i32x4*)(cb + (size_t)((j0)     ^ ml) * 16);
                    u.h[1] = *(const i32x4*)(cb + (size_t)((j0 + 1) ^ ml) * 16);
                    bf[nt] = u.v;
                }
#pragma unroll
                for (int mt = 0; mt < 4; ++mt)
#pragma unroll
                    for (int nt = 0; nt < 4; ++nt)
                        acc[mt][nt] = __builtin_amdgcn_mfma_scale_f32_16x16x128_f8f6f4(
                            af[mt][kc], bf[nt], acc[mt][nt], 0, 0, 0, SC, 0, SC);
            }

            // epilogue: sum exp2(c2*n2i + c2*n2j + m2*dot), weighted
            float ts0 = 0.f, ts1 = 0.f, ts2 = 0.f, ts3 = 0.f;
#pragma unroll
            for (int mt = 0; mt < 4; ++mt)
#pragma unroll
                for (int nt = 0; nt < 4; ++nt) {
                    const float ab = b_j[nt];
                    ts0 += __builtin_amdgcn_exp2f(fmaf(acc[mt][nt][0], m2, a_i[mt][0] + ab));
                    ts1 += __builtin_amdgcn_exp2f(fmaf(acc[mt][nt][1], m2, a_i[mt][1] + ab));
                    ts2 += __builtin_amdgcn_exp2f(fmaf(acc[mt][nt][2], m2, a_i[mt][2] + ab));
                    ts3 += __builtin_amdgcn_exp2f(fmaf(acc[mt][nt][3], m2, a_i[mt][3] + ab));
                }
            const float tsum = (ts0 + ts1) + (ts2 + ts3);

            const float sgn = ((bc < 64) == brX) ? 1.0f : -1.0f;
            const float w   = (bc == br) ? sgn : 2.0f * sgn;   // symmetry weight
            block_acc = fmaf(w, tsum, block_acc);
            cur ^= 1;
        }
        __syncthreads();                  // drain before next strip reuses LDS
    }

    // ---- block reduction + single atomic ----
    float s = block_acc;
#pragma unroll
    for (int off = 32; off; off >>= 1) s += __shfl_down(s, off, 64);
    if (lane == 0) wsum[wave] = s;
    __syncthreads();
    if (t == 0)
        atomicAdd(out, (wsum[0] + wsum[1] + wsum[2] + wsum[3]) * (1.0f / 67108864.0f));
}

// ---------------------------------------------------------------------------
extern "C" void kernel_launch(void* const* d_in, const int* in_sizes, int n_in,
                              void* d_out, int out_size, void* d_ws, size_t ws_size,
                              hipStream_t stream) {
    const float* X      = (const float*)d_in[0];
    const float* Y      = (const float*)d_in[1];
    const int*   sigmap = (const int*)d_in[2];
    float*       out    = (float*)d_out;

    unsigned char* Zf8 = (unsigned char*)d_ws;                        // 4 MB
    float*         n2  = (float*)((char*)d_ws + (size_t)TWO_N * DIM);

    mmd_prep<<<TWO_N / 4, 256, 0, stream>>>(X, Y, sigmap, Zf8, n2, out);
    mmd_main<<<64 * 16, 256, 0, stream>>>(Zf8, n2, sigmap, out);
}